// Round 1
// baseline (1132.408 us; speedup 1.0000x reference)
//
#include <hip/hip_runtime.h>
#include <hip/hip_bf16.h>

// Problem constants
constexpr int BATCH = 64;
constexpr int NTOK  = 197;
constexpr int CDIM  = 768;
constexpr int NH    = 12;
constexpr int HD    = 64;
constexpr int MROWS = BATCH * NTOK;        // 12608
constexpr int LEFT  = 137;                 // int(0.7 * 196)

// Output layout (flat float32, concatenated in return order)
constexpr size_t OUT_OFF_OUT   = 0;                                   // [64,197,768]
constexpr size_t OUT_OFF_INDEX = (size_t)BATCH * NTOK * CDIM;         // 9,682,944  [64,137,768]
constexpr size_t OUT_OFF_IDX   = OUT_OFF_INDEX + (size_t)BATCH * LEFT * CDIM; // 16,415,232 [64,137]
constexpr size_t OUT_OFF_CLS   = OUT_OFF_IDX + (size_t)BATCH * LEFT;  // 16,424,000 [64,196]

// Workspace layout (floats)
constexpr size_t WS_Q     = 0;
constexpr size_t WS_K     = WS_Q + (size_t)MROWS * HD * NH / NH * NH; // 9,682,944 (B*H*N*D)
constexpr size_t WS_V     = WS_K + (size_t)BATCH * NH * NTOK * HD;    // 19,365,888
constexpr size_t WS_AO    = WS_V + (size_t)BATCH * NH * NTOK * HD;    // 29,048,832
constexpr size_t WS_CLSPH = WS_AO + (size_t)MROWS * CDIM;             // 38,731,776 (B*H*196)
constexpr size_t WS_CLSF  = WS_CLSPH + (size_t)BATCH * NH * (NTOK-1); // 38,882,304 (B*196)
constexpr size_t WS_IDXI  = WS_CLSF + (size_t)BATCH * (NTOK-1);       // 38,894,848 (ints, B*137)

// ---------------------------------------------------------------------------
// Tiled fp32 GEMM: O = A @ W^T + bias.  A:[M,K] row-major, W:[N,K] row-major.
// MODE 0: store row-major O0[M,N].
// MODE 1: qkv scatter: N=2304, col -> (which, h, d); store [B,H,NTOK,HD] into
//         O0/O1/O2 = q/k/v.  (64-col block lies entirely in one (which,h).)
// Tiles: 64x64 output, BK=16, 256 threads, 4x4 micro-tile per thread.
// ---------------------------------------------------------------------------
template <int MODE>
__global__ __launch_bounds__(256) void gemm_bias(const float* __restrict__ A,
                                                 const float* __restrict__ W,
                                                 const float* __restrict__ bias,
                                                 float* __restrict__ O0,
                                                 float* __restrict__ O1,
                                                 float* __restrict__ O2,
                                                 int M, int N, int K) {
    __shared__ float As[16][68];   // [k][m], pad 4 keeps float4 alignment, 2-way banks
    __shared__ float Bs[16][68];   // [k][n]

    const int t  = threadIdx.x;
    const int tx = t & 15;
    const int ty = t >> 4;
    const int rowBase = blockIdx.y * 64;
    const int colBase = blockIdx.x * 64;

    const int lr = t >> 2;        // 0..63: row (A) / col (W) within tile
    const int lk = (t & 3) * 4;   // 0,4,8,12: k offset

    const float* Aptr = A + (size_t)(rowBase + lr) * K + lk;
    const float* Wptr = W + (size_t)(colBase + lr) * K + lk;

    float acc[4][4];
#pragma unroll
    for (int i = 0; i < 4; i++)
#pragma unroll
        for (int j = 0; j < 4; j++) acc[i][j] = 0.f;

    for (int k0 = 0; k0 < K; k0 += 16) {
        float4 av = *(const float4*)(Aptr + k0);
        float4 wv = *(const float4*)(Wptr + k0);
        As[lk + 0][lr] = av.x; As[lk + 1][lr] = av.y;
        As[lk + 2][lr] = av.z; As[lk + 3][lr] = av.w;
        Bs[lk + 0][lr] = wv.x; Bs[lk + 1][lr] = wv.y;
        Bs[lk + 2][lr] = wv.z; Bs[lk + 3][lr] = wv.w;
        __syncthreads();
#pragma unroll
        for (int kk = 0; kk < 16; kk++) {
            float4 a  = *(const float4*)&As[kk][ty * 4];
            float4 bv = *(const float4*)&Bs[kk][tx * 4];
            float ar[4] = {a.x, a.y, a.z, a.w};
            float br[4] = {bv.x, bv.y, bv.z, bv.w};
#pragma unroll
            for (int i = 0; i < 4; i++)
#pragma unroll
                for (int j = 0; j < 4; j++) acc[i][j] += ar[i] * br[j];
        }
        __syncthreads();
    }

    float bq[4];
#pragma unroll
    for (int j = 0; j < 4; j++) bq[j] = bias[colBase + tx * 4 + j];

    if (MODE == 0) {
#pragma unroll
        for (int i = 0; i < 4; i++) {
            int row = rowBase + ty * 4 + i;
            float4 r = make_float4(acc[i][0] + bq[0], acc[i][1] + bq[1],
                                   acc[i][2] + bq[2], acc[i][3] + bq[3]);
            *(float4*)&O0[(size_t)row * N + colBase + tx * 4] = r;
        }
    } else {
        const int which = colBase / CDIM;            // 0=q 1=k 2=v (uniform per block)
        const int h     = (colBase % CDIM) >> 6;     // uniform per block
        float* Od = (which == 0) ? O0 : (which == 1) ? O1 : O2;
#pragma unroll
        for (int i = 0; i < 4; i++) {
            int row = rowBase + ty * 4 + i;
            int b = row / NTOK;
            int n = row - b * NTOK;
            size_t off = ((size_t)(b * NH + h) * NTOK + n) * HD + tx * 4;
            float4 r = make_float4(acc[i][0] + bq[0], acc[i][1] + bq[1],
                                   acc[i][2] + bq[2], acc[i][3] + bq[3]);
            *(float4*)&Od[off] = r;
        }
    }
}

// ---------------------------------------------------------------------------
// Attention: one block per (b,h). Online softmax, one thread per query row.
// K/V staged in LDS in 64-key chunks. Writes attn-out [B,N,C] (pre-proj) and
// per-head cls attention row (keys 1..196) for later head-averaging.
// ---------------------------------------------------------------------------
__global__ __launch_bounds__(256) void attn_kernel(const float* __restrict__ Q,
                                                   const float* __restrict__ Kg,
                                                   const float* __restrict__ Vg,
                                                   float* __restrict__ AO,
                                                   float* __restrict__ CLSPH) {
    const int bh = blockIdx.x;           // b*12 + h
    const int b  = bh / NH;
    const int h  = bh - b * NH;
    const int t  = threadIdx.x;

    __shared__ float Ks[64 * 64];
    __shared__ float Vs[64 * 64];
    __shared__ float cls_s[NTOK];
    __shared__ float m0l0[2];

    const size_t head_off = (size_t)bh * NTOK * HD;
    const float* qp = Q + head_off;
    const float* kp = Kg + head_off;
    const float* vp = Vg + head_off;

    float4 qv[16];
    float4 o[16];
    float m = -INFINITY, l = 0.f;
    const int qi = t;
    if (qi < NTOK) {
#pragma unroll
        for (int i = 0; i < 16; i++) qv[i] = *(const float4*)(qp + qi * HD + i * 4);
#pragma unroll
        for (int i = 0; i < 16; i++) o[i] = make_float4(0.f, 0.f, 0.f, 0.f);
    }
    const float scale = 0.125f;  // 64^-0.5

    for (int c0 = 0; c0 < NTOK; c0 += 64) {
        const int cn = min(64, NTOK - c0);
        __syncthreads();   // previous chunk fully consumed before overwrite
        for (int idx = t; idx < cn * 16; idx += 256) {
            ((float4*)Ks)[idx] = *(const float4*)(kp + (size_t)c0 * HD + idx * 4);
            ((float4*)Vs)[idx] = *(const float4*)(vp + (size_t)c0 * HD + idx * 4);
        }
        __syncthreads();
        if (qi < NTOK) {
            for (int j = 0; j < cn; j++) {
                const float4* kr = (const float4*)(Ks + j * HD);
                float s = 0.f;
#pragma unroll
                for (int i = 0; i < 16; i++) {
                    float4 kk4 = kr[i];
                    s += qv[i].x * kk4.x + qv[i].y * kk4.y +
                         qv[i].z * kk4.z + qv[i].w * kk4.w;
                }
                s *= scale;
                if (qi == 0) cls_s[c0 + j] = s;
                float mn    = fmaxf(m, s);
                float alpha = __expf(m - mn);   // exp(-inf)=0 handles first key
                float p     = __expf(s - mn);
                l = l * alpha + p;
                const float4* vr = (const float4*)(Vs + j * HD);
#pragma unroll
                for (int i = 0; i < 16; i++) {
                    float4 vv = vr[i];
                    o[i].x = o[i].x * alpha + p * vv.x;
                    o[i].y = o[i].y * alpha + p * vv.y;
                    o[i].z = o[i].z * alpha + p * vv.z;
                    o[i].w = o[i].w * alpha + p * vv.w;
                }
                m = mn;
            }
        }
    }

    if (qi < NTOK) {
        const float inv = 1.f / l;
        float* op = AO + ((size_t)(b * NTOK + qi)) * CDIM + h * HD;
#pragma unroll
        for (int i = 0; i < 16; i++) {
            float4 r = make_float4(o[i].x * inv, o[i].y * inv, o[i].z * inv, o[i].w * inv);
            *(float4*)(op + i * 4) = r;
        }
    }
    if (qi == 0) { m0l0[0] = m; m0l0[1] = l; }
    __syncthreads();
    if (qi >= 1 && qi < NTOK) {
        float p = __expf(cls_s[qi] - m0l0[0]) / m0l0[1];
        CLSPH[(size_t)bh * (NTOK - 1) + (qi - 1)] = p;
    }
}

// ---------------------------------------------------------------------------
// cls_attn = mean over heads; write to ws (for topk) and to d_out cls region.
// ---------------------------------------------------------------------------
__global__ void cls_mean_kernel(const float* __restrict__ CLSPH,
                                float* __restrict__ clsF,
                                float* __restrict__ outCls) {
    int tid = blockIdx.x * 256 + threadIdx.x;
    if (tid >= BATCH * (NTOK - 1)) return;
    int b = tid / (NTOK - 1);
    int j = tid - b * (NTOK - 1);
    float s = 0.f;
#pragma unroll
    for (int h = 0; h < NH; h++) s += CLSPH[(size_t)(b * NH + h) * (NTOK - 1) + j];
    float v = s * (1.f / 12.f);
    clsF[tid]   = v;
    outCls[tid] = v;
}

// ---------------------------------------------------------------------------
// Top-k per batch by exact rank counting: descending value, ascending index
// tie-break (== stable descending sort, matches jax.lax.top_k / np argsort).
// ---------------------------------------------------------------------------
__global__ void topk_kernel(const float* __restrict__ clsF,
                            int* __restrict__ idxI,
                            float* __restrict__ idxOut) {
    const int b = blockIdx.x;
    const int t = threadIdx.x;
    __shared__ float v[NTOK - 1];
    if (t < NTOK - 1) v[t] = clsF[b * (NTOK - 1) + t];
    __syncthreads();
    if (t < NTOK - 1) {
        float vi = v[t];
        int rank = 0;
        for (int j = 0; j < NTOK - 1; j++) {
            float vj = v[j];
            rank += (vj > vi) || (vj == vi && j < t);
        }
        if (rank < LEFT) {
            idxI[b * LEFT + rank]   = t;
            idxOut[b * LEFT + rank] = (float)t;
        }
    }
}

// index = broadcast idx over channel dim: [B,137,768]
__global__ void fill_index_kernel(const int* __restrict__ idxI,
                                  float* __restrict__ dst) {
    int tid = blockIdx.x * 256 + threadIdx.x;
    if (tid >= BATCH * LEFT * CDIM) return;
    dst[tid] = (float)idxI[tid / CDIM];
}

extern "C" void kernel_launch(void* const* d_in, const int* in_sizes, int n_in,
                              void* d_out, int out_size, void* d_ws, size_t ws_size,
                              hipStream_t stream) {
    const float* x      = (const float*)d_in[0];
    const float* qkv_w  = (const float*)d_in[1];  // [2304,768]
    const float* qkv_b  = (const float*)d_in[2];  // [2304]
    const float* proj_w = (const float*)d_in[3];  // [768,768]
    const float* proj_b = (const float*)d_in[4];  // [768]
    float* out = (float*)d_out;

    float* ws    = (float*)d_ws;
    float* q     = ws + WS_Q;
    float* k     = ws + WS_K;
    float* v     = ws + WS_V;
    float* ao    = ws + WS_AO;
    float* clsph = ws + WS_CLSPH;
    float* clsf  = ws + WS_CLSF;
    int*   idxi  = (int*)(ws + WS_IDXI);

    // 1) QKV projection + scatter to [B,H,N,D]
    gemm_bias<1><<<dim3(3 * CDIM / 64, MROWS / 64), 256, 0, stream>>>(
        x, qkv_w, qkv_b, q, k, v, MROWS, 3 * CDIM, CDIM);

    // 2) Attention per (b,h): writes pre-proj out [B,N,C] + per-head cls rows
    attn_kernel<<<BATCH * NH, 256, 0, stream>>>(q, k, v, ao, clsph);

    // 3) Output projection
    gemm_bias<0><<<dim3(CDIM / 64, MROWS / 64), 256, 0, stream>>>(
        ao, proj_w, proj_b, out + OUT_OFF_OUT, nullptr, nullptr, MROWS, CDIM, CDIM);

    // 4) Head-average cls attention
    cls_mean_kernel<<<(BATCH * (NTOK - 1) + 255) / 256, 256, 0, stream>>>(
        clsph, clsf, out + OUT_OFF_CLS);

    // 5) Exact top-137 (stable descending)
    topk_kernel<<<BATCH, 256, 0, stream>>>(clsf, idxi, out + OUT_OFF_IDX);

    // 6) Broadcast indices over channels
    fill_index_kernel<<<((size_t)BATCH * LEFT * CDIM + 255) / 256, 256, 0, stream>>>(
        idxi, out + OUT_OFF_INDEX);
}

// Round 3
// 752.871 us; speedup vs baseline: 1.5041x; 1.5041x over previous
//
#include <hip/hip_runtime.h>
#include <hip/hip_bf16.h>
#include <stdint.h>

// Problem constants
constexpr int BATCH = 64;
constexpr int NTOK  = 197;
constexpr int CDIM  = 768;
constexpr int NH    = 12;
constexpr int HD    = 64;
constexpr int MROWS = BATCH * NTOK;        // 12608
constexpr int MPAD  = 12672;               // 99 * 128
constexpr int LEFT  = 137;                 // int(0.7 * 196)

// Output layout (flat float32, concatenated in return order)
constexpr size_t OUT_OFF_OUT   = 0;                                   // [64,197,768]
constexpr size_t OUT_OFF_INDEX = (size_t)BATCH * NTOK * CDIM;         // [64,137,768]
constexpr size_t OUT_OFF_IDX   = OUT_OFF_INDEX + (size_t)BATCH * LEFT * CDIM; // [64,137]
constexpr size_t OUT_OFF_CLS   = OUT_OFF_IDX + (size_t)BATCH * LEFT;  // [64,196]

// Workspace layout (in float units)
constexpr size_t WS_Q     = 0;                                        // B*H*N*D
constexpr size_t WS_K     = WS_Q  + (size_t)BATCH * NH * NTOK * HD;
constexpr size_t WS_V     = WS_K  + (size_t)BATCH * NH * NTOK * HD;
constexpr size_t WS_AO    = WS_V  + (size_t)BATCH * NH * NTOK * HD;   // [MROWS, C]
constexpr size_t WS_CLSPH = WS_AO + (size_t)MROWS * CDIM;             // B*H*196
constexpr size_t WS_CLSF  = WS_CLSPH + (size_t)BATCH * NH * (NTOK-1);
constexpr size_t WS_IDXI  = WS_CLSF  + (size_t)BATCH * (NTOK-1);
constexpr size_t WS_Q0    = WS_IDXI + (size_t)BATCH * LEFT;           // [64,768] exact q row0
// bf16 hi/lo buffers (sizes counted in float units = elems/2)
constexpr size_t WS_XHI   = WS_Q0  + (size_t)BATCH * CDIM;            // [MPAD,768] bf16
constexpr size_t WS_XLO   = WS_XHI + (size_t)MPAD * CDIM / 2;
constexpr size_t WS_WHI   = WS_XLO + (size_t)MPAD * CDIM / 2;         // [2304,768] bf16
constexpr size_t WS_WLO   = WS_WHI + (size_t)3 * CDIM * CDIM / 2;
constexpr size_t WS_PHI   = WS_WLO + (size_t)3 * CDIM * CDIM / 2;     // [768,768] bf16
constexpr size_t WS_PLO   = WS_PHI + (size_t)CDIM * CDIM / 2;
// ao_hi/ao_lo alias x_hi/x_lo (x dead after QKV GEMM)

typedef __attribute__((ext_vector_type(8))) short short8;
typedef __attribute__((ext_vector_type(4))) float floatx4;

__device__ __forceinline__ ushort f2bf(float x) {
    __hip_bfloat16 h = __float2bfloat16(x);
    return *(ushort*)&h;
}
__device__ __forceinline__ float bf2f(ushort u) {
    __hip_bfloat16 h; *(ushort*)&h = u;
    return __bfloat162float(h);
}

// async global->LDS, 16B per lane; LDS dest must be wave-uniform base + lane*16
__device__ __forceinline__ void load_lds16(const ushort* g, ushort* l) {
    __builtin_amdgcn_global_load_lds(
        (const __attribute__((address_space(1))) uint32_t*)(uintptr_t)g,
        (__attribute__((address_space(3))) uint32_t*)(uint32_t)(uintptr_t)l,
        16, 0, 0);
}

// ---------------------------------------------------------------------------
// Split fp32 -> (bf16 hi, bf16 lo), with zero padding up to npad4 float4s.
// ---------------------------------------------------------------------------
__global__ __launch_bounds__(256) void split_kernel(const float* __restrict__ src,
                                                    ushort* __restrict__ hi,
                                                    ushort* __restrict__ lo,
                                                    int n4, int npad4) {
    int i = blockIdx.x * 256 + threadIdx.x;
    if (i >= npad4) return;
    ushort4 h4, l4;
    if (i < n4) {
        float4 a = ((const float4*)src)[i];
        float f[4] = {a.x, a.y, a.z, a.w};
        ushort hv[4], lv[4];
#pragma unroll
        for (int j = 0; j < 4; j++) {
            hv[j] = f2bf(f[j]);
            lv[j] = f2bf(f[j] - bf2f(hv[j]));
        }
        h4 = make_ushort4(hv[0], hv[1], hv[2], hv[3]);
        l4 = make_ushort4(lv[0], lv[1], lv[2], lv[3]);
    } else {
        h4 = make_ushort4(0, 0, 0, 0);
        l4 = make_ushort4(0, 0, 0, 0);
    }
    ((ushort4*)hi)[i] = h4;
    ((ushort4*)lo)[i] = l4;
}

// ---------------------------------------------------------------------------
// Exact fp32 q row-0 projection: q0[b, c] = x[b,0,:] . qkv_w[c,:] + qkv_b[c]
// (c in 0..767 = q-part rows of qkv_w)
// ---------------------------------------------------------------------------
__global__ __launch_bounds__(256) void q0_kernel(const float* __restrict__ x,
                                                 const float* __restrict__ qkv_w,
                                                 const float* __restrict__ qkv_b,
                                                 float* __restrict__ q0) {
    int tid = blockIdx.x * 256 + threadIdx.x;
    if (tid >= BATCH * CDIM) return;
    int b = tid / CDIM, c = tid - b * CDIM;
    const float* xr = x + (size_t)b * NTOK * CDIM;   // token 0 of batch b
    const float* wr = qkv_w + (size_t)c * CDIM;
    float s = 0.f;
    for (int k = 0; k < CDIM; k += 4) {
        float4 xv = *(const float4*)(xr + k);
        float4 wv = *(const float4*)(wr + k);
        s += xv.x * wv.x + xv.y * wv.y + xv.z * wv.z + xv.w * wv.w;
    }
    q0[tid] = s + qkv_b[c];
}

// ---------------------------------------------------------------------------
// Exact fp32 cls attention row. One block per (b,h).
//   u_c  = sum_d q0[b,h,d] * Wk[h*64+d, c]         (Wk = qkv_w rows 768..1535)
//   s_j  = (u . x[b,j,:] + q0[b,h,:] . bk) * scale
//   CLSPH[bh, j-1] = exp(s_j - max)/sum   over all 197 keys
// ---------------------------------------------------------------------------
__global__ __launch_bounds__(256) void cls_score_kernel(const float* __restrict__ x,
                                                        const float* __restrict__ qkv_w,
                                                        const float* __restrict__ qkv_b,
                                                        const float* __restrict__ q0,
                                                        float* __restrict__ CLSPH) {
    const int bh = blockIdx.x;
    const int b  = bh / NH;
    const int h  = bh - b * NH;
    const int t  = threadIdx.x;

    __shared__ float u[CDIM];
    __shared__ float sc[NTOK];
    __shared__ float red[2];

    const float* q0p = q0 + (size_t)b * CDIM + h * HD;
    const float* wk  = qkv_w + (size_t)(CDIM + h * HD) * CDIM;   // k-part rows

    float ua = 0.f, ub = 0.f, uc = 0.f;
    for (int d = 0; d < HD; d++) {
        float qd = q0p[d];
        const float* row = wk + (size_t)d * CDIM;
        ua = fmaf(qd, row[t],       ua);
        ub = fmaf(qd, row[t + 256], ub);
        uc = fmaf(qd, row[t + 512], uc);
    }
    u[t] = ua; u[t + 256] = ub; u[t + 512] = uc;
    __syncthreads();

    if (t < NTOK) {
        const float* xr = x + ((size_t)b * NTOK + t) * CDIM;
        float s = 0.f;
        for (int c = 0; c < CDIM; c += 4) {
            float4 xv = *(const float4*)(xr + c);
            s += u[c] * xv.x + u[c + 1] * xv.y + u[c + 2] * xv.z + u[c + 3] * xv.w;
        }
        float qb = 0.f;
        const float* bk = qkv_b + CDIM + h * HD;
        for (int d = 0; d < HD; d++) qb = fmaf(q0p[d], bk[d], qb);
        sc[t] = (s + qb) * 0.125f;
    }
    __syncthreads();
    if (t == 0) {
        float m = -INFINITY;
        for (int j = 0; j < NTOK; j++) m = fmaxf(m, sc[j]);
        float l = 0.f;
        for (int j = 0; j < NTOK; j++) l += expf(sc[j] - m);
        red[0] = m; red[1] = l;
    }
    __syncthreads();
    if (t >= 1 && t < NTOK) {
        CLSPH[(size_t)bh * (NTOK - 1) + (t - 1)] = expf(sc[t] - red[0]) / red[1];
    }
}

// ---------------------------------------------------------------------------
// Split-bf16 MFMA GEMM: O = (Ahi+Alo) @ (Whi+Wlo)^T + bias (lo*lo dropped).
// 128x128 tile, BK=32, 256 threads = 4 waves, each wave 4x4 of 16x16x32 MFMA.
// MODE 0: row-major O0[Mvalid, N].   MODE 1: qkv scatter to q/k/v [B,H,N,D].
// ---------------------------------------------------------------------------
template <int MODE>
__global__ __launch_bounds__(256) void mfma_gemm(const ushort* __restrict__ Ahi,
                                                 const ushort* __restrict__ Alo,
                                                 const ushort* __restrict__ Whi,
                                                 const ushort* __restrict__ Wlo,
                                                 const float* __restrict__ bias,
                                                 float* __restrict__ O0,
                                                 float* __restrict__ O1,
                                                 float* __restrict__ O2,
                                                 int Mvalid, int N, int K) {
    __shared__ ushort sAh[128 * 32], sAl[128 * 32], sBh[128 * 32], sBl[128 * 32];

    const int t    = threadIdx.x;
    const int lane = t & 63;
    const int w    = t >> 6;
    const int wm   = (w & 1) * 64;
    const int wn   = (w >> 1) * 64;
    const int rowBase = blockIdx.y * 128;
    const int colBase = blockIdx.x * 128;

    floatx4 acc[4][4];
#pragma unroll
    for (int i = 0; i < 4; i++)
#pragma unroll
        for (int j = 0; j < 4; j++)
#pragma unroll
            for (int r = 0; r < 4; r++) acc[i][j][r] = 0.f;

    const int srow = t >> 2;
    const int skp  = (t & 3) * 8;
    const ushort* gAh0 = Ahi + (size_t)(rowBase + srow) * K + skp;
    const ushort* gAl0 = Alo + (size_t)(rowBase + srow) * K + skp;
    const ushort* gBh0 = Whi + (size_t)(colBase + srow) * K + skp;
    const ushort* gBl0 = Wlo + (size_t)(colBase + srow) * K + skp;
    const size_t rstep = (size_t)64 * K;
    const int fr = lane & 15;
    const int fq = lane >> 4;

    for (int k0 = 0; k0 < K; k0 += 32) {
        __syncthreads();
        load_lds16(gAh0 + k0,         sAh + t * 8);
        load_lds16(gAh0 + k0 + rstep, sAh + t * 8 + 2048);
        load_lds16(gAl0 + k0,         sAl + t * 8);
        load_lds16(gAl0 + k0 + rstep, sAl + t * 8 + 2048);
        load_lds16(gBh0 + k0,         sBh + t * 8);
        load_lds16(gBh0 + k0 + rstep, sBh + t * 8 + 2048);
        load_lds16(gBl0 + k0,         sBl + t * 8);
        load_lds16(gBl0 + k0 + rstep, sBl + t * 8 + 2048);
        __syncthreads();

        short8 ah[4], al[4], bh[4], bl[4];
#pragma unroll
        for (int i = 0; i < 4; i++) {
            ah[i] = *(const short8*)&sAh[(wm + i * 16 + fr) * 32 + fq * 8];
            al[i] = *(const short8*)&sAl[(wm + i * 16 + fr) * 32 + fq * 8];
            bh[i] = *(const short8*)&sBh[(wn + i * 16 + fr) * 32 + fq * 8];
            bl[i] = *(const short8*)&sBl[(wn + i * 16 + fr) * 32 + fq * 8];
        }
#pragma unroll
        for (int i = 0; i < 4; i++)
#pragma unroll
            for (int j = 0; j < 4; j++) {
                acc[i][j] = __builtin_amdgcn_mfma_f32_16x16x32_bf16(ah[i], bh[j], acc[i][j], 0, 0, 0);
                acc[i][j] = __builtin_amdgcn_mfma_f32_16x16x32_bf16(al[i], bh[j], acc[i][j], 0, 0, 0);
                acc[i][j] = __builtin_amdgcn_mfma_f32_16x16x32_bf16(ah[i], bl[j], acc[i][j], 0, 0, 0);
            }
    }

    // epilogue: C/D layout col(n)=lane&15, row(m)=(lane>>4)*4+reg
#pragma unroll
    for (int j = 0; j < 4; j++) {
        const int n  = colBase + wn + j * 16 + fr;
        const float bv = bias[n];
        if (MODE == 0) {
#pragma unroll
            for (int i = 0; i < 4; i++) {
                const int mb = rowBase + wm + i * 16 + fq * 4;
#pragma unroll
                for (int r = 0; r < 4; r++) {
                    const int m = mb + r;
                    if (m < Mvalid) O0[(size_t)m * N + n] = acc[i][j][r] + bv;
                }
            }
        } else {
            const int which = n / CDIM;
            const int nc    = n - which * CDIM;
            const int h     = nc >> 6;
            const int d     = nc & 63;
            float* Od = (which == 0) ? O0 : (which == 1) ? O1 : O2;
#pragma unroll
            for (int i = 0; i < 4; i++) {
                const int mb = rowBase + wm + i * 16 + fq * 4;
#pragma unroll
                for (int r = 0; r < 4; r++) {
                    const int m = mb + r;
                    if (m < Mvalid) {
                        const int b   = m / NTOK;
                        const int tok = m - b * NTOK;
                        Od[((size_t)(b * NH + h) * NTOK + tok) * HD + d] = acc[i][j][r] + bv;
                    }
                }
            }
        }
    }
}

// ---------------------------------------------------------------------------
// Attention: one block per (b,h). Online softmax, one thread per query row.
// K/V staged in LDS in 64-key chunks. Writes attn-out [B,N,C] (pre-proj).
// ---------------------------------------------------------------------------
__global__ __launch_bounds__(256) void attn_kernel(const float* __restrict__ Q,
                                                   const float* __restrict__ Kg,
                                                   const float* __restrict__ Vg,
                                                   float* __restrict__ AO) {
    const int bh = blockIdx.x;
    const int b  = bh / NH;
    const int h  = bh - b * NH;
    const int t  = threadIdx.x;

    __shared__ float Ks[64 * 64];
    __shared__ float Vs[64 * 64];

    const size_t head_off = (size_t)bh * NTOK * HD;
    const float* qp = Q + head_off;
    const float* kp = Kg + head_off;
    const float* vp = Vg + head_off;

    float4 qv[16];
    float4 o[16];
    float m = -INFINITY, l = 0.f;
    const int qi = t;
    if (qi < NTOK) {
#pragma unroll
        for (int i = 0; i < 16; i++) qv[i] = *(const float4*)(qp + qi * HD + i * 4);
#pragma unroll
        for (int i = 0; i < 16; i++) o[i] = make_float4(0.f, 0.f, 0.f, 0.f);
    }
    const float scale = 0.125f;

    for (int c0 = 0; c0 < NTOK; c0 += 64) {
        const int cn = min(64, NTOK - c0);
        __syncthreads();
        for (int idx = t; idx < cn * 16; idx += 256) {
            ((float4*)Ks)[idx] = *(const float4*)(kp + (size_t)c0 * HD + idx * 4);
            ((float4*)Vs)[idx] = *(const float4*)(vp + (size_t)c0 * HD + idx * 4);
        }
        __syncthreads();
        if (qi < NTOK) {
            for (int j = 0; j < cn; j++) {
                const float4* kr = (const float4*)(Ks + j * HD);
                float s = 0.f;
#pragma unroll
                for (int i = 0; i < 16; i++) {
                    float4 kk4 = kr[i];
                    s += qv[i].x * kk4.x + qv[i].y * kk4.y +
                         qv[i].z * kk4.z + qv[i].w * kk4.w;
                }
                s *= scale;
                float mn    = fmaxf(m, s);
                float alpha = __expf(m - mn);
                float p     = __expf(s - mn);
                l = l * alpha + p;
                const float4* vr = (const float4*)(Vs + j * HD);
#pragma unroll
                for (int i = 0; i < 16; i++) {
                    float4 vv = vr[i];
                    o[i].x = o[i].x * alpha + p * vv.x;
                    o[i].y = o[i].y * alpha + p * vv.y;
                    o[i].z = o[i].z * alpha + p * vv.z;
                    o[i].w = o[i].w * alpha + p * vv.w;
                }
                m = mn;
            }
        }
    }

    if (qi < NTOK) {
        const float inv = 1.f / l;
        float* op = AO + ((size_t)(b * NTOK + qi)) * CDIM + h * HD;
#pragma unroll
        for (int i = 0; i < 16; i++) {
            float4 r = make_float4(o[i].x * inv, o[i].y * inv, o[i].z * inv, o[i].w * inv);
            *(float4*)(op + i * 4) = r;
        }
    }
}

// ---------------------------------------------------------------------------
__global__ void cls_mean_kernel(const float* __restrict__ CLSPH,
                                float* __restrict__ clsF,
                                float* __restrict__ outCls) {
    int tid = blockIdx.x * 256 + threadIdx.x;
    if (tid >= BATCH * (NTOK - 1)) return;
    int b = tid / (NTOK - 1);
    int j = tid - b * (NTOK - 1);
    float s = 0.f;
#pragma unroll
    for (int h = 0; h < NH; h++) s += CLSPH[(size_t)(b * NH + h) * (NTOK - 1) + j];
    float v = s * (1.f / 12.f);
    clsF[tid]   = v;
    outCls[tid] = v;
}

__global__ void topk_kernel(const float* __restrict__ clsF,
                            int* __restrict__ idxI,
                            float* __restrict__ idxOut) {
    const int b = blockIdx.x;
    const int t = threadIdx.x;
    __shared__ float v[NTOK - 1];
    if (t < NTOK - 1) v[t] = clsF[b * (NTOK - 1) + t];
    __syncthreads();
    if (t < NTOK - 1) {
        float vi = v[t];
        int rank = 0;
        for (int j = 0; j < NTOK - 1; j++) {
            float vj = v[j];
            rank += (vj > vi) || (vj == vi && j < t);
        }
        if (rank < LEFT) {
            idxI[b * LEFT + rank]   = t;
            idxOut[b * LEFT + rank] = (float)t;
        }
    }
}

__global__ void fill_index_kernel(const int* __restrict__ idxI,
                                  float* __restrict__ dst) {
    int tid = blockIdx.x * 256 + threadIdx.x;
    if (tid >= BATCH * LEFT * CDIM) return;
    dst[tid] = (float)idxI[tid / CDIM];
}

extern "C" void kernel_launch(void* const* d_in, const int* in_sizes, int n_in,
                              void* d_out, int out_size, void* d_ws, size_t ws_size,
                              hipStream_t stream) {
    const float* x      = (const float*)d_in[0];
    const float* qkv_w  = (const float*)d_in[1];  // [2304,768]
    const float* qkv_b  = (const float*)d_in[2];  // [2304]
    const float* proj_w = (const float*)d_in[3];  // [768,768]
    const float* proj_b = (const float*)d_in[4];  // [768]
    float* out = (float*)d_out;

    float*  ws    = (float*)d_ws;
    float*  q     = ws + WS_Q;
    float*  k     = ws + WS_K;
    float*  v     = ws + WS_V;
    float*  ao    = ws + WS_AO;
    float*  clsph = ws + WS_CLSPH;
    float*  clsf  = ws + WS_CLSF;
    int*    idxi  = (int*)(ws + WS_IDXI);
    float*  q0    = ws + WS_Q0;
    ushort* xhi   = (ushort*)(ws + WS_XHI);
    ushort* xlo   = (ushort*)(ws + WS_XLO);
    ushort* whi   = (ushort*)(ws + WS_WHI);
    ushort* wlo   = (ushort*)(ws + WS_WLO);
    ushort* phi   = (ushort*)(ws + WS_PHI);
    ushort* plo   = (ushort*)(ws + WS_PLO);
    ushort* aohi  = xhi;   // alias: x_hi dead after QKV GEMM
    ushort* aolo  = xlo;

    // 1) fp32 -> bf16 hi/lo splits
    {
        int n4 = MROWS * CDIM / 4, np4 = MPAD * CDIM / 4;
        split_kernel<<<(np4 + 255) / 256, 256, 0, stream>>>(x, xhi, xlo, n4, np4);
        int w4 = 3 * CDIM * CDIM / 4;
        split_kernel<<<(w4 + 255) / 256, 256, 0, stream>>>(qkv_w, whi, wlo, w4, w4);
        int p4 = CDIM * CDIM / 4;
        split_kernel<<<(p4 + 255) / 256, 256, 0, stream>>>(proj_w, phi, plo, p4, p4);
    }

    // 2) Exact fp32 cls-score side path (top-k precision domain)
    q0_kernel<<<(BATCH * CDIM + 255) / 256, 256, 0, stream>>>(x, qkv_w, qkv_b, q0);
    cls_score_kernel<<<BATCH * NH, 256, 0, stream>>>(x, qkv_w, qkv_b, q0, clsph);

    // 3) QKV projection (split-bf16 MFMA) + scatter to [B,H,N,D]
    mfma_gemm<1><<<dim3(3 * CDIM / 128, MPAD / 128), 256, 0, stream>>>(
        xhi, xlo, whi, wlo, qkv_b, q, k, v, MROWS, 3 * CDIM, CDIM);

    // 4) Attention per (b,h)
    attn_kernel<<<BATCH * NH, 256, 0, stream>>>(q, k, v, ao);

    // 5) Split attention output, then output projection (split-bf16 MFMA)
    {
        int n4 = MROWS * CDIM / 4, np4 = MPAD * CDIM / 4;
        split_kernel<<<(np4 + 255) / 256, 256, 0, stream>>>(ao, aohi, aolo, n4, np4);
    }
    mfma_gemm<0><<<dim3(CDIM / 128, MPAD / 128), 256, 0, stream>>>(
        aohi, aolo, phi, plo, proj_b, out + OUT_OFF_OUT, nullptr, nullptr,
        MROWS, CDIM, CDIM);

    // 6) Head-average cls attention (from exact path)
    cls_mean_kernel<<<(BATCH * (NTOK - 1) + 255) / 256, 256, 0, stream>>>(
        clsph, clsf, out + OUT_OFF_CLS);

    // 7) Exact top-137 (stable descending)
    topk_kernel<<<BATCH, 256, 0, stream>>>(clsf, idxi, out + OUT_OFF_IDX);

    // 8) Broadcast indices over channels
    fill_index_kernel<<<((size_t)BATCH * LEFT * CDIM + 255) / 256, 256, 0, stream>>>(
        idxi, out + OUT_OFF_INDEX);
}